// Round 5
// baseline (1075.966 us; speedup 1.0000x reference)
//
#include <hip/hip_runtime.h>
#include <hip/hip_bf16.h>
#include <stdint.h>

typedef __bf16 bf16;
typedef __bf16 bf16x8 __attribute__((ext_vector_type(8)));
typedef float f32x4 __attribute__((ext_vector_type(4)));
typedef uint32_t u32x4 __attribute__((ext_vector_type(4)));

#define HD 128
#define LDP (HD + 8)
#define NTPB 4
#define MFMA __builtin_amdgcn_mfma_f32_16x16x32_bf16

__device__ inline float bflo(uint32_t u){ return __uint_as_float(u << 16); }
__device__ inline float bfhi(uint32_t u){ return __uint_as_float(u & 0xffff0000u); }
__device__ inline uint32_t packbf(float a, float b){
    bf16 x = (bf16)a, y = (bf16)b;
    uint16_t ux = __builtin_bit_cast(uint16_t, x), uy = __builtin_bit_cast(uint16_t, y);
    return (uint32_t)ux | ((uint32_t)uy << 16);
}
__device__ inline bf16x8 ldb8(const bf16* p){ return *(const bf16x8*)p; }
__device__ inline float sigm(float x){ return 1.f / (1.f + __expf(-x)); }
__device__ inline float tanh_fast(float x){ float t = __expf(-2.f * x); return (1.f - t) / (1.f + t); }
__device__ inline uint32_t swz(uint32_t b){ return b ^ (((b >> 8) & 7u) << 4); }

// ---------------- weight / activation conversion ----------------
__global__ void k_cvt(const float* __restrict__ in, bf16* __restrict__ out, int n){
    int i = blockIdx.x * 256 + threadIdx.x;
    if (i < n) out[i] = (bf16)in[i];
}

// ---------------- CSR (only the unsorted half needs building) ----------------
__global__ void k_bound(const int* __restrict__ dstB, int E, int* __restrict__ rows2, int n){
    int v = blockIdx.x * 256 + threadIdx.x;
    if (v > n) return;
    int lo = 0, hi = E;
    while (lo < hi){ int mid = (lo + hi) >> 1; if (dstB[mid] < v) lo = mid + 1; else hi = mid; }
    rows2[v] = lo;
}

__global__ void k_count(const int* __restrict__ dst, int* __restrict__ deg, int ne){
    int i = blockIdx.x * 256 + threadIdx.x;
    if (i < ne) atomicAdd(&deg[dst[i]], 1);
}

__global__ void k_scan1(const int* __restrict__ deg, int* __restrict__ rows,
                        int* __restrict__ bsum, int n){
    __shared__ int lds[256];
    int b = blockIdx.x, tid = threadIdx.x;
    int i0 = b * 1024 + tid * 4;
    int v[4]; int s = 0;
#pragma unroll
    for (int j = 0; j < 4; ++j){ int idx = i0 + j; v[j] = (idx < n) ? deg[idx] : 0; s += v[j]; }
    lds[tid] = s; __syncthreads();
    int acc = s;
    for (int off = 1; off < 256; off <<= 1){
        int add = (tid >= off) ? lds[tid - off] : 0;
        __syncthreads();
        acc += add; lds[tid] = acc;
        __syncthreads();
    }
    int run = acc - s;
#pragma unroll
    for (int j = 0; j < 4; ++j){ int idx = i0 + j; if (idx < n) rows[idx] = run; run += v[j]; }
    if (tid == 255) bsum[b] = acc;
}

__global__ void k_scan2(int* __restrict__ bsum, int nb){
    __shared__ int lds[128];
    int tid = threadIdx.x;
    int v = (tid < nb) ? bsum[tid] : 0;
    lds[tid] = v; __syncthreads();
    int acc = v;
    for (int off = 1; off < 128; off <<= 1){
        int add = (tid >= off) ? lds[tid - off] : 0;
        __syncthreads();
        acc += add; lds[tid] = acc;
        __syncthreads();
    }
    if (tid < nb) bsum[tid] = acc - v;
}

__global__ void k_scan3(int* __restrict__ rows, const int* __restrict__ bsum, int n, int total){
    int i = blockIdx.x * 256 + threadIdx.x;
    if (i < n) rows[i] += bsum[i >> 10];
    if (i == n) rows[n] = total;
}

__global__ void k_fill(const int* __restrict__ src, const int* __restrict__ dst,
                       int* __restrict__ cur, int* __restrict__ col, int ne){
    int i = blockIdx.x * 256 + threadIdx.x;
    if (i < ne){ int p = atomicAdd(&cur[dst[i]], 1); col[p] = src[i]; }
}

// ---------------- mean aggregation: 8 neighbors in flight per wave ----------------
__global__ __launch_bounds__(256) void k_gather(
    const bf16* __restrict__ curx,
    const int* __restrict__ srcB, const int* __restrict__ rows2,
    const int* __restrict__ colB, const int* __restrict__ rowsB,
    bf16* __restrict__ cout, int n)
{
    int wid = threadIdx.x >> 6, lane = threadIdx.x & 63;
    int v = blockIdx.x * 4 + wid;
    if (v >= n) return;
    int grp = lane >> 3, sl = lane & 7;
    int a0 = rows2[v], a1 = rows2[v + 1];
    int b0 = rowsB[v], b1 = rowsB[v + 1];
    int deg = (a1 - a0) + (b1 - b0);
    float inv = (deg > 0) ? 1.f / (float)deg : 0.f;

    const u32x4* base = (const u32x4*)curx;
    float acc[16];
#pragma unroll
    for (int k = 0; k < 16; ++k) acc[k] = 0.f;

    for (int j = a0 + grp; j < a1; j += 8){
        int nb = srcB[j];
        u32x4 q0 = base[(size_t)nb * 16 + sl];
        u32x4 q1 = base[(size_t)nb * 16 + 8 + sl];
#pragma unroll
        for (int k = 0; k < 4; ++k){
            acc[2*k]   += bflo(q0[k]); acc[2*k+1]   += bfhi(q0[k]);
            acc[8+2*k] += bflo(q1[k]); acc[8+2*k+1] += bfhi(q1[k]);
        }
    }
    for (int j = b0 + grp; j < b1; j += 8){
        int nb = colB[j];
        u32x4 q0 = base[(size_t)nb * 16 + sl];
        u32x4 q1 = base[(size_t)nb * 16 + 8 + sl];
#pragma unroll
        for (int k = 0; k < 4; ++k){
            acc[2*k]   += bflo(q0[k]); acc[2*k+1]   += bfhi(q0[k]);
            acc[8+2*k] += bflo(q1[k]); acc[8+2*k+1] += bfhi(q1[k]);
        }
    }
#pragma unroll
    for (int k = 0; k < 16; ++k){
        acc[k] += __shfl_xor(acc[k], 8);
        acc[k] += __shfl_xor(acc[k], 16);
        acc[k] += __shfl_xor(acc[k], 32);
    }
    if (grp == 0){
        u32x4 x0 = base[(size_t)v * 16 + sl];
        u32x4 x1 = base[(size_t)v * 16 + 8 + sl];
        u32x4 o0, o1;
#pragma unroll
        for (int k = 0; k < 4; ++k){
            o0[k] = packbf(bflo(x0[k]) + acc[2*k] * inv,   bfhi(x0[k]) + acc[2*k+1] * inv);
            o1[k] = packbf(bflo(x1[k]) + acc[8+2*k] * inv, bfhi(x1[k]) + acc[8+2*k+1] * inv);
        }
        ((u32x4*)cout)[(size_t)v * 16 + sl]     = o0;
        ((u32x4*)cout)[(size_t)v * 16 + 8 + sl] = o1;
    }
}

// ---------------- MLP+BN, weight-stationary, in-place, barrier-free tile loop ----------------
// 512 thr = 8 waves x 16 rows. W1+W2 (64KB) staged once; per-wave 4KB act slab.
__global__ __launch_bounds__(512, 2) void k_mlp(
    bf16* __restrict__ cio,
    const bf16* __restrict__ W1g, const float* __restrict__ b1,
    const bf16* __restrict__ W2g, const float* __restrict__ b2,
    const float* __restrict__ gm, const float* __restrict__ bt,
    const float* __restrict__ mu, const float* __restrict__ vr, int nT128)
{
    __shared__ __align__(16) char wsm[65536];
    __shared__ __align__(16) char actm[32768];
    int tid = threadIdx.x, wid = tid >> 6, lane = tid & 63;
    int rA = lane & 15, u = lane >> 4, ko = u * 8;

    // stage W1 (32KB -> wsm[0:32K]) + W2 (32KB -> wsm[32K:64K]), inverse-swizzled source
#pragma unroll
    for (int i = 0; i < 8; ++i){
        int c = i * 8 + wid;
        uint32_t o = (uint32_t)c * 1024;
        const char* base = (c < 32) ? (const char*)W1g : (const char*)W2g;
        uint32_t po = (o & 32767u) + (uint32_t)lane * 16;
        __builtin_amdgcn_global_load_lds(
            (const __attribute__((address_space(1))) void*)(base + swz(po)),
            (__attribute__((address_space(3))) void*)(wsm + o), 16, 0, 0);
    }
    __syncthreads();

    char* act = actm + wid * 4096;
    auto ldw = [&](uint32_t regionOff, int t, int kk)->bf16x8 {
        uint32_t b = regionOff + (uint32_t)(t*16 + rA)*256 + (uint32_t)u*16 + (uint32_t)kk*64;
        return *(const bf16x8*)(wsm + swz(b));
    };
    auto actw = [&](int r, int c, bf16 val){
        uint32_t b = (uint32_t)r*256 + (uint32_t)c*2;
        *(bf16*)(act + swz(b)) = val;
    };
    auto actr = [&](int r, int kk)->bf16x8 {
        uint32_t b = (uint32_t)r*256 + (uint32_t)(ko + kk*32)*2;
        return *(const bf16x8*)(act + swz(b));
    };

    for (int t = blockIdx.x; t < nT128; t += gridDim.x){
        int r0 = t * 128 + wid * 16;
        bf16x8 a[4];
        const bf16* ap = cio + (size_t)(r0 + rA) * HD + ko;
#pragma unroll
        for (int kk = 0; kk < 4; ++kk) a[kk] = ldb8(ap + kk * 32);

#pragma unroll
        for (int tt = 0; tt < 8; ++tt){
            f32x4 acc = {0,0,0,0};
#pragma unroll
            for (int kk = 0; kk < 4; ++kk)
                acc = MFMA(a[kk], ldw(0, tt, kk), acc, 0, 0, 0);
            int c = tt*16 + rA;
            float bias = b1[c];
#pragma unroll
            for (int j = 0; j < 4; ++j)
                actw(u*4 + j, c, (bf16)fmaxf(acc[j] + bias, 0.f));
        }
        __threadfence_block();
        bf16x8 a2[4];
#pragma unroll
        for (int kk = 0; kk < 4; ++kk) a2[kk] = actr(rA, kk);

#pragma unroll
        for (int tt = 0; tt < 8; ++tt){
            f32x4 acc = {0,0,0,0};
#pragma unroll
            for (int kk = 0; kk < 4; ++kk)
                acc = MFMA(a2[kk], ldw(32768u, tt, kk), acc, 0, 0, 0);
            int c = tt*16 + rA;
            float s = gm[c] * rsqrtf(vr[c] + 1e-5f);
            float o = bt[c] - mu[c] * s;
            float bias = b2[c];
#pragma unroll
            for (int j = 0; j < 4; ++j)
                cio[(size_t)(r0 + u*4 + j) * HD + c] = (bf16)((acc[j] + bias) * s + o);
        }
        __threadfence_block();
    }
}

// ---------------- GRU, weight-stationary, unit-sliced (4 groups of 32 units) ----------------
// Block = 4 waves x 32 rows = 128-row tiles; ug = blockIdx&3 selects 32 units.
// 6 panels (r/z/n x ih/hh, 32x128 each) = 48KB LDS -> 3 blocks/CU. Reads h_old, writes h_new.
__global__ __launch_bounds__(256, 3) void k_gru(
    const bf16* __restrict__ cbn, const bf16* __restrict__ hOld, bf16* __restrict__ hNew,
    const bf16* __restrict__ Wih, const bf16* __restrict__ Whh,
    const float* __restrict__ bih, const float* __restrict__ bhh, int nT128)
{
    __shared__ __align__(16) char wsm[49152];
    int tid = threadIdx.x, wid = tid >> 6, lane = tid & 63;
    int ug = blockIdx.x & 3;
    int rA = lane & 15, u = lane >> 4, ko = u * 8;

    // panel p = g*2+m : m=0 -> Wih, m=1 -> Whh; rows (units) g*128 + ug*32 ..+31
#pragma unroll
    for (int i = 0; i < 12; ++i){
        int c = i * 4 + wid;                  // 1KB chunk id, 0..47
        uint32_t o = (uint32_t)c * 1024;
        int p = o >> 13;                      // panel
        int g = p >> 1, m = p & 1;
        const char* base = (const char*)(m ? Whh : Wih) + ((size_t)(g * 128 + ug * 32)) * 256;
        uint32_t po = (o & 8191u) + (uint32_t)lane * 16;
        __builtin_amdgcn_global_load_lds(
            (const __attribute__((address_space(1))) void*)(base + swz(po)),
            (__attribute__((address_space(3))) void*)(wsm + o), 16, 0, 0);
    }
    __syncthreads();

    auto ldw = [&](int p, int ct, int kk)->bf16x8 {
        uint32_t b = (uint32_t)p*8192 + (uint32_t)(ct*16 + rA)*256 + (uint32_t)u*16 + (uint32_t)kk*64;
        return *(const bf16x8*)(wsm + swz(b));
    };

    int nB = (int)(gridDim.x >> 2);
    for (int t = (int)(blockIdx.x >> 2); t < nT128; t += nB){
        int r0 = t * 128 + wid * 32;
        bf16x8 ac[2][4], ah[2][4];
#pragma unroll
        for (int m = 0; m < 2; ++m){
            const bf16* cp = cbn  + (size_t)(r0 + m*16 + rA) * HD + ko;
            const bf16* hp = hOld + (size_t)(r0 + m*16 + rA) * HD + ko;
#pragma unroll
            for (int kk = 0; kk < 4; ++kk){ ac[m][kk] = ldb8(cp + kk*32); ah[m][kk] = ldb8(hp + kk*32); }
        }
#pragma unroll
        for (int ct = 0; ct < 2; ++ct){
            f32x4 rr0={0,0,0,0}, rr1={0,0,0,0}, zz0={0,0,0,0}, zz1={0,0,0,0};
            f32x4 gi0={0,0,0,0}, gi1={0,0,0,0}, gh0={0,0,0,0}, gh1={0,0,0,0};
#pragma unroll
            for (int kk = 0; kk < 4; ++kk){
                bf16x8 Bri = ldw(0, ct, kk), Brh = ldw(1, ct, kk);
                bf16x8 Bzi = ldw(2, ct, kk), Bzh = ldw(3, ct, kk);
                bf16x8 Bni = ldw(4, ct, kk), Bnh = ldw(5, ct, kk);
                rr0 = MFMA(ac[0][kk], Bri, rr0, 0, 0, 0);
                rr1 = MFMA(ac[1][kk], Bri, rr1, 0, 0, 0);
                rr0 = MFMA(ah[0][kk], Brh, rr0, 0, 0, 0);
                rr1 = MFMA(ah[1][kk], Brh, rr1, 0, 0, 0);
                zz0 = MFMA(ac[0][kk], Bzi, zz0, 0, 0, 0);
                zz1 = MFMA(ac[1][kk], Bzi, zz1, 0, 0, 0);
                zz0 = MFMA(ah[0][kk], Bzh, zz0, 0, 0, 0);
                zz1 = MFMA(ah[1][kk], Bzh, zz1, 0, 0, 0);
                gi0 = MFMA(ac[0][kk], Bni, gi0, 0, 0, 0);
                gi1 = MFMA(ac[1][kk], Bni, gi1, 0, 0, 0);
                gh0 = MFMA(ah[0][kk], Bnh, gh0, 0, 0, 0);
                gh1 = MFMA(ah[1][kk], Bnh, gh1, 0, 0, 0);
            }
            int c = ug * 32 + ct * 16 + rA;
            float br = bih[c] + bhh[c];
            float bz = bih[c + 128] + bhh[c + 128];
            float bin = bih[c + 256], bhn = bhh[c + 256];
#pragma unroll
            for (int j = 0; j < 4; ++j){
                size_t i0 = (size_t)(r0 + u*4 + j) * HD + c;
                size_t i1 = (size_t)(r0 + 16 + u*4 + j) * HD + c;
                float h0 = (float)hOld[i0], h1 = (float)hOld[i1];
                float rg0 = sigm(rr0[j] + br), rg1 = sigm(rr1[j] + br);
                float zg0 = sigm(zz0[j] + bz), zg1 = sigm(zz1[j] + bz);
                float ng0 = tanh_fast(gi0[j] + bin + rg0 * (gh0[j] + bhn));
                float ng1 = tanh_fast(gi1[j] + bin + rg1 * (gh1[j] + bhn));
                hNew[i0] = (bf16)((1.f - zg0) * ng0 + zg0 * h0);
                hNew[i1] = (bf16)((1.f - zg1) * ng1 + zg1 * h1);
            }
        }
    }
}

// ---------------- final MLP: 128 -> 128 (ReLU) -> 64, f32 out ----------------
__global__ __launch_bounds__(256) void k_final(
    const bf16* __restrict__ hin, const bf16* __restrict__ W1, const float* __restrict__ b1,
    const bf16* __restrict__ W2, const float* __restrict__ b2,
    float* __restrict__ out, int nTiles)
{
    __shared__ bf16 lds[NTPB][16][LDP];
    int wid = threadIdx.x >> 6, lane = threadIdx.x & 63;
    int tile = blockIdx.x * NTPB + wid;
    if (tile >= nTiles) return;
    int r0 = tile * 16;
    int rA = lane & 15, u = lane >> 4, ko = u * 8;

    bf16x8 a[4];
    const bf16* ap = hin + (size_t)(r0 + rA) * HD + ko;
#pragma unroll
    for (int kk = 0; kk < 4; ++kk) a[kk] = ldb8(ap + kk * 32);

#pragma unroll
    for (int t = 0; t < 8; ++t){
        f32x4 acc = {0.f, 0.f, 0.f, 0.f};
        int c = t * 16 + rA;
        const bf16* bp = W1 + (size_t)c * HD + ko;
#pragma unroll
        for (int kk = 0; kk < 4; ++kk)
            acc = MFMA(a[kk], ldb8(bp + kk * 32), acc, 0, 0, 0);
        float bias = b1[c];
#pragma unroll
        for (int j = 0; j < 4; ++j){
            float v = fmaxf(acc[j] + bias, 0.f);
            lds[wid][u * 4 + j][c] = (bf16)v;
        }
    }
    __threadfence_block();
    bf16x8 a2[4];
    const bf16* lp = &lds[wid][rA][ko];
#pragma unroll
    for (int kk = 0; kk < 4; ++kk) a2[kk] = ldb8(lp + kk * 32);

#pragma unroll
    for (int t = 0; t < 4; ++t){
        f32x4 acc = {0.f, 0.f, 0.f, 0.f};
        int c = t * 16 + rA;
        const bf16* bp = W2 + (size_t)c * HD + ko;
#pragma unroll
        for (int kk = 0; kk < 4; ++kk)
            acc = MFMA(a2[kk], ldb8(bp + kk * 32), acc, 0, 0, 0);
        float bias = b2[c];
#pragma unroll
        for (int j = 0; j < 4; ++j)
            out[(size_t)(r0 + u * 4 + j) * 64 + c] = acc[j] + bias;
    }
}

extern "C" void kernel_launch(void* const* d_in, const int* in_sizes, int n_in,
                              void* d_out, int out_size, void* d_ws, size_t ws_size,
                              hipStream_t stream)
{
    const float* x    = (const float*)d_in[0];
    const int*   src  = (const int*)d_in[1];
    const int*   dst  = (const int*)d_in[2];
    const float* lW1  = (const float*)d_in[3];
    const float* lb1  = (const float*)d_in[4];
    const float* lW2  = (const float*)d_in[5];
    const float* lb2  = (const float*)d_in[6];
    const float* gmm  = (const float*)d_in[7];
    const float* bta  = (const float*)d_in[8];
    const float* mun  = (const float*)d_in[9];
    const float* vrr  = (const float*)d_in[10];
    const float* Wih  = (const float*)d_in[11];
    const float* Whh  = (const float*)d_in[12];
    const float* bih  = (const float*)d_in[13];
    const float* bhh  = (const float*)d_in[14];
    const float* fW1  = (const float*)d_in[15];
    const float* fb1  = (const float*)d_in[16];
    const float* fW2  = (const float*)d_in[17];
    const float* fb2  = (const float*)d_in[18];

    int n  = in_sizes[0] / HD;
    int ne = in_sizes[1];
    int E  = ne / 2;                    // dst[E:2E) is sorted
    int L  = in_sizes[3] / (HD * HD);
    int nPad = (n + 127) & ~127;

    char* w = (char*)d_ws;
    auto alloc = [&](size_t bytes) -> char* {
        char* p = w; w += (bytes + 255) & ~(size_t)255; return p;
    };
    bf16* xbf  = (bf16*)alloc((size_t)nPad * HD * 2);
    bf16* hA   = (bf16*)alloc((size_t)nPad * HD * 2);
    bf16* hB   = (bf16*)alloc((size_t)nPad * HD * 2);
    bf16* cin  = (bf16*)alloc((size_t)nPad * HD * 2);
    bf16* W1b  = (bf16*)alloc((size_t)L * HD * HD * 2);
    bf16* W2b  = (bf16*)alloc((size_t)L * HD * HD * 2);
    bf16* Wib  = (bf16*)alloc((size_t)3 * HD * HD * 2);
    bf16* Whb  = (bf16*)alloc((size_t)3 * HD * HD * 2);
    bf16* fW1b = (bf16*)alloc((size_t)HD * HD * 2);
    bf16* fW2b = (bf16*)alloc((size_t)64 * HD * 2);
    int*  degB = (int*)alloc((size_t)n * 4);
    int*  rowsB= (int*)alloc((size_t)(n + 1) * 4);
    int*  rows2= (int*)alloc((size_t)(n + 1) * 4);
    int*  bsum = (int*)alloc(512);
    int*  curB = (int*)alloc((size_t)n * 4);
    int*  colB = (int*)alloc((size_t)E * 4);

    auto cvt = [&](const float* i, bf16* o, int cnt){
        k_cvt<<<(cnt + 255) / 256, 256, 0, stream>>>(i, o, cnt);
    };
    cvt(x,   xbf,  n * HD);
    cvt(lW1, W1b,  L * HD * HD);
    cvt(lW2, W2b,  L * HD * HD);
    cvt(Wih, Wib,  3 * HD * HD);
    cvt(Whh, Whb,  3 * HD * HD);
    cvt(fW1, fW1b, HD * HD);
    cvt(fW2, fW2b, 64 * HD);

    hipMemsetAsync(degB, 0, (size_t)n * 4, stream);
    hipMemsetAsync(hA, 0, (size_t)nPad * HD * 2, stream);

    k_bound<<<(n + 1 + 255) / 256, 256, 0, stream>>>(dst + E, E, rows2, n);
    k_count<<<(E + 255) / 256, 256, 0, stream>>>(dst, degB, E);
    int nb = (n + 1023) / 1024;
    k_scan1<<<nb, 256, 0, stream>>>(degB, rowsB, bsum, n);
    k_scan2<<<1, 128, 0, stream>>>(bsum, nb);
    k_scan3<<<(n + 1 + 255) / 256, 256, 0, stream>>>(rowsB, bsum, n, E);
    hipMemcpyAsync(curB, rowsB, (size_t)n * 4, hipMemcpyDeviceToDevice, stream);
    k_fill<<<(E + 255) / 256, 256, 0, stream>>>(src, dst, curB, colB, E);

    int nT128 = nPad / 128;
    int nT16 = (n + 15) / 16;
    int gF = (nT16 + NTPB - 1) / NTPB;

    const bf16* curp = xbf;
    for (int l = 0; l < L; ++l){
        k_gather<<<(n + 3) / 4, 256, 0, stream>>>(curp, src + E, rows2, colB, rowsB, cin, n);
        k_mlp<<<256, 512, 0, stream>>>(cin,
            W1b + (size_t)l * HD * HD, lb1 + l * HD,
            W2b + (size_t)l * HD * HD, lb2 + l * HD,
            gmm + l * HD, bta + l * HD, mun + l * HD, vrr + l * HD, nT128);
        k_gru<<<768, 256, 0, stream>>>(cin, hA, hB, Wib, Whb, bih, bhh, nT128);
        bf16* tmp = hA; hA = hB; hB = tmp;
        curp = hA;
    }
    k_final<<<gF, 256, 0, stream>>>(hA, fW1b, fb1, fW2b, fb2, (float*)d_out, nT16);
}

// Round 6
// 928.823 us; speedup vs baseline: 1.1584x; 1.1584x over previous
//
#include <hip/hip_runtime.h>
#include <hip/hip_bf16.h>
#include <stdint.h>

typedef __bf16 bf16;
typedef __bf16 bf16x8 __attribute__((ext_vector_type(8)));
typedef float f32x4 __attribute__((ext_vector_type(4)));
typedef uint32_t u32x4 __attribute__((ext_vector_type(4)));

#define HD 128
#define LDP (HD + 8)
#define NTPB 4
#define MFMA __builtin_amdgcn_mfma_f32_16x16x32_bf16

__device__ inline float bflo(uint32_t u){ return __uint_as_float(u << 16); }
__device__ inline float bfhi(uint32_t u){ return __uint_as_float(u & 0xffff0000u); }
__device__ inline uint32_t packbf(float a, float b){
    bf16 x = (bf16)a, y = (bf16)b;
    uint16_t ux = __builtin_bit_cast(uint16_t, x), uy = __builtin_bit_cast(uint16_t, y);
    return (uint32_t)ux | ((uint32_t)uy << 16);
}
__device__ inline bf16x8 ldb8(const bf16* p){ return *(const bf16x8*)p; }
__device__ inline float sigm(float x){ return 1.f / (1.f + __expf(-x)); }
__device__ inline float tanh_fast(float x){ float t = __expf(-2.f * x); return (1.f - t) / (1.f + t); }
// 16B-slot swizzle within a 256B row: slot ^= row&7. Self-inverse.
__device__ inline uint32_t swz(uint32_t b){ return b ^ (((b >> 8) & 7u) << 4); }

// ---------------- weight conversion (plain) ----------------
__global__ void k_cvt(const float* __restrict__ in, bf16* __restrict__ out, int n){
    int i = blockIdx.x * 256 + threadIdx.x;
    if (i < n) out[i] = (bf16)in[i];
}

// ---------------- x conversion with per-row slot swizzle ----------------
__global__ void k_cvt_x(const float* __restrict__ in, uint32_t* __restrict__ out, int nU){
    int i = blockIdx.x * 256 + threadIdx.x;   // u32 index (2 bf16)
    if (i >= nU) return;
    int r = i >> 6, dw = i & 63;
    uint32_t v = packbf(in[(size_t)i * 2], in[(size_t)i * 2 + 1]);
    int slot = dw >> 2, w = dw & 3;
    out[(size_t)r * 64 + (((slot ^ (r & 7)) << 2) | w)] = v;
}

// ---------------- CSR (only the unsorted half needs building) ----------------
__global__ void k_bound(const int* __restrict__ dstB, int E, int* __restrict__ rows2, int n){
    int v = blockIdx.x * 256 + threadIdx.x;
    if (v > n) return;
    int lo = 0, hi = E;
    while (lo < hi){ int mid = (lo + hi) >> 1; if (dstB[mid] < v) lo = mid + 1; else hi = mid; }
    rows2[v] = lo;
}

__global__ void k_count(const int* __restrict__ dst, int* __restrict__ deg, int ne){
    int i = blockIdx.x * 256 + threadIdx.x;
    if (i < ne) atomicAdd(&deg[dst[i]], 1);
}

__global__ void k_scan1(const int* __restrict__ deg, int* __restrict__ rows,
                        int* __restrict__ bsum, int n){
    __shared__ int lds[256];
    int b = blockIdx.x, tid = threadIdx.x;
    int i0 = b * 1024 + tid * 4;
    int v[4]; int s = 0;
#pragma unroll
    for (int j = 0; j < 4; ++j){ int idx = i0 + j; v[j] = (idx < n) ? deg[idx] : 0; s += v[j]; }
    lds[tid] = s; __syncthreads();
    int acc = s;
    for (int off = 1; off < 256; off <<= 1){
        int add = (tid >= off) ? lds[tid - off] : 0;
        __syncthreads();
        acc += add; lds[tid] = acc;
        __syncthreads();
    }
    int run = acc - s;
#pragma unroll
    for (int j = 0; j < 4; ++j){ int idx = i0 + j; if (idx < n) rows[idx] = run; run += v[j]; }
    if (tid == 255) bsum[b] = acc;
}

__global__ void k_scan2(int* __restrict__ bsum, int nb){
    __shared__ int lds[128];
    int tid = threadIdx.x;
    int v = (tid < nb) ? bsum[tid] : 0;
    lds[tid] = v; __syncthreads();
    int acc = v;
    for (int off = 1; off < 128; off <<= 1){
        int add = (tid >= off) ? lds[tid - off] : 0;
        __syncthreads();
        acc += add; lds[tid] = acc;
        __syncthreads();
    }
    if (tid < nb) bsum[tid] = acc - v;
}

__global__ void k_scan3(int* __restrict__ rows, const int* __restrict__ bsum, int n, int total){
    int i = blockIdx.x * 256 + threadIdx.x;
    if (i < n) rows[i] += bsum[i >> 10];
    if (i == n) rows[n] = total;
}

__global__ void k_fill(const int* __restrict__ src, const int* __restrict__ dst,
                       int* __restrict__ cur, int* __restrict__ col, int ne){
    int i = blockIdx.x * 256 + threadIdx.x;
    if (i < ne){ int p = atomicAdd(&cur[dst[i]], 1); col[p] = src[i]; }
}

// ---------------- mean aggregation over swizzled rows ----------------
__global__ __launch_bounds__(256) void k_gather(
    const bf16* __restrict__ curx,
    const int* __restrict__ srcB, const int* __restrict__ rows2,
    const int* __restrict__ colB, const int* __restrict__ rowsB,
    bf16* __restrict__ cout, int n)
{
    int wid = threadIdx.x >> 6, lane = threadIdx.x & 63;
    int v = blockIdx.x * 4 + wid;
    if (v >= n) return;
    int grp = lane >> 3, sl = lane & 7;
    int a0 = rows2[v], a1 = rows2[v + 1];
    int b0 = rowsB[v], b1 = rowsB[v + 1];
    int deg = (a1 - a0) + (b1 - b0);
    float inv = (deg > 0) ? 1.f / (float)deg : 0.f;

    const u32x4* base = (const u32x4*)curx;
    float acc[16];
#pragma unroll
    for (int k = 0; k < 16; ++k) acc[k] = 0.f;

    for (int j = a0 + grp; j < a1; j += 8){
        int nb = srcB[j];
        int px = nb & 7;
        u32x4 q0 = base[(size_t)nb * 16 + (sl ^ px)];
        u32x4 q1 = base[(size_t)nb * 16 + 8 + (sl ^ px)];
#pragma unroll
        for (int k = 0; k < 4; ++k){
            acc[2*k]   += bflo(q0[k]); acc[2*k+1]   += bfhi(q0[k]);
            acc[8+2*k] += bflo(q1[k]); acc[8+2*k+1] += bfhi(q1[k]);
        }
    }
    for (int j = b0 + grp; j < b1; j += 8){
        int nb = colB[j];
        int px = nb & 7;
        u32x4 q0 = base[(size_t)nb * 16 + (sl ^ px)];
        u32x4 q1 = base[(size_t)nb * 16 + 8 + (sl ^ px)];
#pragma unroll
        for (int k = 0; k < 4; ++k){
            acc[2*k]   += bflo(q0[k]); acc[2*k+1]   += bfhi(q0[k]);
            acc[8+2*k] += bflo(q1[k]); acc[8+2*k+1] += bfhi(q1[k]);
        }
    }
#pragma unroll
    for (int k = 0; k < 16; ++k){
        acc[k] += __shfl_xor(acc[k], 8);
        acc[k] += __shfl_xor(acc[k], 16);
        acc[k] += __shfl_xor(acc[k], 32);
    }
    if (grp == 0){
        int pv = v & 7;
        u32x4 x0 = base[(size_t)v * 16 + (sl ^ pv)];
        u32x4 x1 = base[(size_t)v * 16 + 8 + (sl ^ pv)];
        u32x4 o0, o1;
#pragma unroll
        for (int k = 0; k < 4; ++k){
            o0[k] = packbf(bflo(x0[k]) + acc[2*k] * inv,   bfhi(x0[k]) + acc[2*k+1] * inv);
            o1[k] = packbf(bflo(x1[k]) + acc[8+2*k] * inv, bfhi(x1[k]) + acc[8+2*k+1] * inv);
        }
        ((u32x4*)cout)[(size_t)v * 16 + (sl ^ pv)]     = o0;
        ((u32x4*)cout)[(size_t)v * 16 + 8 + (sl ^ pv)] = o1;
    }
}

// ---------------- fused Layer: wave-stationary weights, async LDS activation tiles ----
// 512 thr = 8 waves; wave w owns output cols w*16..w*16+15 for MLP and all 3 GRU gates.
// LDS 128KB: c-tile dbuf (2x32K) + h-tile (32K) + act1 (32K). All tiles slot-swizzled.
#define CL0 0u
#define CL1 32768u
#define HL0 65536u
#define ALO 98304u
__global__ __launch_bounds__(512, 2) void k_layer(
    const bf16* __restrict__ cin, const bf16* __restrict__ hOld, bf16* __restrict__ hNew,
    const bf16* __restrict__ W1, const float* __restrict__ b1,
    const bf16* __restrict__ W2, const float* __restrict__ b2,
    const float* __restrict__ gm, const float* __restrict__ bt,
    const float* __restrict__ mu, const float* __restrict__ vr,
    const bf16* __restrict__ Wih, const bf16* __restrict__ Whh,
    const float* __restrict__ bih, const float* __restrict__ bhh, int nT)
{
    __shared__ __align__(16) char smem[131072];
    int tid = threadIdx.x, wid = tid >> 6, lane = tid & 63;
    int rA = lane & 15, u = lane >> 4, ko = u * 8;
    int c = wid * 16 + rA;                       // this lane's output column

    // ---- weights -> registers (once per block) ----
    bf16x8 W1f[4], W2f[4], Gri[4], Grh[4], Gzi[4], Gzh[4], Gni[4], Gnh[4];
#pragma unroll
    for (int kk = 0; kk < 4; ++kk){
        W1f[kk] = ldb8(W1  + (size_t)c * HD + ko + kk * 32);
        W2f[kk] = ldb8(W2  + (size_t)c * HD + ko + kk * 32);
        Gri[kk] = ldb8(Wih + (size_t)c * HD + ko + kk * 32);
        Gzi[kk] = ldb8(Wih + (size_t)(c + 128) * HD + ko + kk * 32);
        Gni[kk] = ldb8(Wih + (size_t)(c + 256) * HD + ko + kk * 32);
        Grh[kk] = ldb8(Whh + (size_t)c * HD + ko + kk * 32);
        Gzh[kk] = ldb8(Whh + (size_t)(c + 128) * HD + ko + kk * 32);
        Gnh[kk] = ldb8(Whh + (size_t)(c + 256) * HD + ko + kk * 32);
    }
    float b1c = b1[c];
    float bnS = gm[c] * rsqrtf(vr[c] + 1e-5f);
    float bnO = bt[c] - mu[c] * bnS;
    float b2c = b2[c];
    float br = bih[c] + bhh[c], bz = bih[c + 128] + bhh[c + 128];
    float bin = bih[c + 256], bhn = bhh[c + 256];

    auto gload = [&](const char* g, uint32_t lo){
        __builtin_amdgcn_global_load_lds(
            (const __attribute__((address_space(1))) void*)g,
            (__attribute__((address_space(3))) void*)(smem + lo), 16, 0, 0);
    };
    auto stageC = [&](int t, uint32_t dst){
        const char* g = (const char*)cin + (size_t)t * 32768 + (size_t)lane * 16;
#pragma unroll
        for (int i = 0; i < 4; ++i){
            uint32_t ch = (uint32_t)(wid * 4 + i) * 1024;
            gload(g + ch, dst + ch);
        }
    };
    auto stageH = [&](int t){
        const char* g = (const char*)hOld + (size_t)t * 32768 + (size_t)lane * 16;
#pragma unroll
        for (int i = 0; i < 4; ++i){
            uint32_t ch = (uint32_t)(wid * 4 + i) * 1024;
            gload(g + ch, HL0 + ch);
        }
    };

    int t = blockIdx.x;
    int cur = 0;
    if (t < nT) stageC(t, CL0);
    for (; t < nT; t += (int)gridDim.x){
        __syncthreads();                          // drains stage of c(t) (+ all)
        stageH(t);                                // 4 issues (oldest)
        int tn = t + (int)gridDim.x;
        if (tn < nT) stageC(tn, cur ? CL0 : CL1); // 4 issues (newest, fly all tile)
        uint32_t CB = cur ? CL1 : CL0;

        // ---- GEMM1 + ReLU -> act1 ----
#pragma unroll
        for (int m = 0; m < 8; ++m){
            bf16x8 a_[4];
#pragma unroll
            for (int kk = 0; kk < 4; ++kk){
                uint32_t b = (uint32_t)(m * 16 + rA) * 256 + (uint32_t)(u * 16 + kk * 64);
                a_[kk] = *(const bf16x8*)(smem + CB + swz(b));
            }
            f32x4 acc = {0,0,0,0};
#pragma unroll
            for (int kk = 0; kk < 4; ++kk) acc = MFMA(a_[kk], W1f[kk], acc, 0, 0, 0);
#pragma unroll
            for (int j = 0; j < 4; ++j){
                uint32_t r = (uint32_t)(m * 16 + u * 4 + j);
                *(bf16*)(smem + ALO + swz(r * 256 + (uint32_t)c * 2)) =
                    (bf16)fmaxf(acc[j] + b1c, 0.f);
            }
        }
        asm volatile("s_waitcnt lgkmcnt(0)" ::: "memory");
        __builtin_amdgcn_sched_barrier(0);
        __builtin_amdgcn_s_barrier();

        // ---- GEMM2 + BN -> c-tile (overwrites consumed cin) ----
#pragma unroll
        for (int m = 0; m < 8; ++m){
            bf16x8 a_[4];
#pragma unroll
            for (int kk = 0; kk < 4; ++kk){
                uint32_t b = (uint32_t)(m * 16 + rA) * 256 + (uint32_t)(u * 16 + kk * 64);
                a_[kk] = *(const bf16x8*)(smem + ALO + swz(b));
            }
            f32x4 acc = {0,0,0,0};
#pragma unroll
            for (int kk = 0; kk < 4; ++kk) acc = MFMA(a_[kk], W2f[kk], acc, 0, 0, 0);
#pragma unroll
            for (int j = 0; j < 4; ++j){
                uint32_t r = (uint32_t)(m * 16 + u * 4 + j);
                *(bf16*)(smem + CB + swz(r * 256 + (uint32_t)c * 2)) =
                    (bf16)((acc[j] + b2c) * bnS + bnO);
            }
        }
        // h(t) must be landed (4 oldest); c(t+1) may stay in flight (4 newest)
        if (tn < nT){ asm volatile("s_waitcnt vmcnt(4) lgkmcnt(0)" ::: "memory"); }
        else        { asm volatile("s_waitcnt vmcnt(0) lgkmcnt(0)" ::: "memory"); }
        __builtin_amdgcn_sched_barrier(0);
        __builtin_amdgcn_s_barrier();

        // ---- GRU ----
        char* hNb = (char*)hNew + (size_t)t * 32768;
#pragma unroll
        for (int m = 0; m < 8; ++m){
            bf16x8 ac_[4], ah_[4];
#pragma unroll
            for (int kk = 0; kk < 4; ++kk){
                uint32_t b = (uint32_t)(m * 16 + rA) * 256 + (uint32_t)(u * 16 + kk * 64);
                ac_[kk] = *(const bf16x8*)(smem + CB + swz(b));
                ah_[kk] = *(const bf16x8*)(smem + HL0 + swz(b));
            }
            f32x4 rr = {0,0,0,0}, zz = {0,0,0,0}, gi = {0,0,0,0}, gh = {0,0,0,0};
#pragma unroll
            for (int kk = 0; kk < 4; ++kk){
                rr = MFMA(ac_[kk], Gri[kk], rr, 0, 0, 0);
                rr = MFMA(ah_[kk], Grh[kk], rr, 0, 0, 0);
                zz = MFMA(ac_[kk], Gzi[kk], zz, 0, 0, 0);
                zz = MFMA(ah_[kk], Gzh[kk], zz, 0, 0, 0);
                gi = MFMA(ac_[kk], Gni[kk], gi, 0, 0, 0);
                gh = MFMA(ah_[kk], Gnh[kk], gh, 0, 0, 0);
            }
#pragma unroll
            for (int j = 0; j < 4; ++j){
                uint32_t r = (uint32_t)(m * 16 + u * 4 + j);
                uint32_t inner = swz(r * 256 + (uint32_t)c * 2);
                float hold = (float)*(const bf16*)(smem + HL0 + inner);
                float rg = sigm(rr[j] + br);
                float zg = sigm(zz[j] + bz);
                float ng = tanh_fast(gi[j] + bin + rg * (gh[j] + bhn));
                *(bf16*)(hNb + inner) = (bf16)((1.f - zg) * ng + zg * hold);
            }
        }
        cur ^= 1;
    }
}

// ---------------- final MLP: 128 -> 128 (ReLU) -> 64, f32 out ----------------
__global__ __launch_bounds__(256) void k_final(
    const bf16* __restrict__ hin, const bf16* __restrict__ W1, const float* __restrict__ b1,
    const bf16* __restrict__ W2, const float* __restrict__ b2,
    float* __restrict__ out, int nTiles)
{
    __shared__ bf16 lds[NTPB][16][LDP];
    int wid = threadIdx.x >> 6, lane = threadIdx.x & 63;
    int tile = blockIdx.x * NTPB + wid;
    if (tile >= nTiles) return;
    int r0 = tile * 16;
    int rA = lane & 15, u = lane >> 4, ko = u * 8;

    // hin rows are slot-swizzled
    bf16x8 a[4];
    const char* hb = (const char*)hin;
    uint32_t b0 = (uint32_t)(r0 + rA) * 256 + (uint32_t)(u * 16);
#pragma unroll
    for (int kk = 0; kk < 4; ++kk) a[kk] = *(const bf16x8*)(hb + swz(b0 + (uint32_t)kk * 64));

#pragma unroll
    for (int t = 0; t < 8; ++t){
        f32x4 acc = {0.f, 0.f, 0.f, 0.f};
        int c = t * 16 + rA;
        const bf16* bp = W1 + (size_t)c * HD + ko;
#pragma unroll
        for (int kk = 0; kk < 4; ++kk)
            acc = MFMA(a[kk], ldb8(bp + kk * 32), acc, 0, 0, 0);
        float bias = b1[c];
#pragma unroll
        for (int j = 0; j < 4; ++j){
            float v = fmaxf(acc[j] + bias, 0.f);
            lds[wid][u * 4 + j][c] = (bf16)v;
        }
    }
    __threadfence_block();
    bf16x8 a2[4];
    const bf16* lp = &lds[wid][rA][ko];
#pragma unroll
    for (int kk = 0; kk < 4; ++kk) a2[kk] = ldb8(lp + kk * 32);

#pragma unroll
    for (int t = 0; t < 4; ++t){
        f32x4 acc = {0.f, 0.f, 0.f, 0.f};
        int c = t * 16 + rA;
        const bf16* bp = W2 + (size_t)c * HD + ko;
#pragma unroll
        for (int kk = 0; kk < 4; ++kk)
            acc = MFMA(a2[kk], ldb8(bp + kk * 32), acc, 0, 0, 0);
        float bias = b2[c];
#pragma unroll
        for (int j = 0; j < 4; ++j)
            out[(size_t)(r0 + u * 4 + j) * 64 + c] = acc[j] + bias;
    }
}

extern "C" void kernel_launch(void* const* d_in, const int* in_sizes, int n_in,
                              void* d_out, int out_size, void* d_ws, size_t ws_size,
                              hipStream_t stream)
{
    const float* x    = (const float*)d_in[0];
    const int*   src  = (const int*)d_in[1];
    const int*   dst  = (const int*)d_in[2];
    const float* lW1  = (const float*)d_in[3];
    const float* lb1  = (const float*)d_in[4];
    const float* lW2  = (const float*)d_in[5];
    const float* lb2  = (const float*)d_in[6];
    const float* gmm  = (const float*)d_in[7];
    const float* bta  = (const float*)d_in[8];
    const float* mun  = (const float*)d_in[9];
    const float* vrr  = (const float*)d_in[10];
    const float* Wih  = (const float*)d_in[11];
    const float* Whh  = (const float*)d_in[12];
    const float* bih  = (const float*)d_in[13];
    const float* bhh  = (const float*)d_in[14];
    const float* fW1  = (const float*)d_in[15];
    const float* fb1  = (const float*)d_in[16];
    const float* fW2  = (const float*)d_in[17];
    const float* fb2  = (const float*)d_in[18];

    int n  = in_sizes[0] / HD;
    int ne = in_sizes[1];
    int E  = ne / 2;                    // dst[E:2E) is sorted
    int L  = in_sizes[3] / (HD * HD);
    int nPad = (n + 127) & ~127;

    char* w = (char*)d_ws;
    auto alloc = [&](size_t bytes) -> char* {
        char* p = w; w += (bytes + 255) & ~(size_t)255; return p;
    };
    bf16* xbf  = (bf16*)alloc((size_t)nPad * HD * 2);
    bf16* hA   = (bf16*)alloc((size_t)nPad * HD * 2);
    bf16* hB   = (bf16*)alloc((size_t)nPad * HD * 2);
    bf16* cin  = (bf16*)alloc((size_t)nPad * HD * 2);
    bf16* W1b  = (bf16*)alloc((size_t)L * HD * HD * 2);
    bf16* W2b  = (bf16*)alloc((size_t)L * HD * HD * 2);
    bf16* Wib  = (bf16*)alloc((size_t)3 * HD * HD * 2);
    bf16* Whb  = (bf16*)alloc((size_t)3 * HD * HD * 2);
    bf16* fW1b = (bf16*)alloc((size_t)HD * HD * 2);
    bf16* fW2b = (bf16*)alloc((size_t)64 * HD * 2);
    int*  degB = (int*)alloc((size_t)n * 4);
    int*  rowsB= (int*)alloc((size_t)(n + 1) * 4);
    int*  rows2= (int*)alloc((size_t)(n + 1) * 4);
    int*  bsum = (int*)alloc(512);
    int*  curB = (int*)alloc((size_t)n * 4);
    int*  colB = (int*)alloc((size_t)E * 4);

    auto cvt = [&](const float* i, bf16* o, int cnt){
        k_cvt<<<(cnt + 255) / 256, 256, 0, stream>>>(i, o, cnt);
    };
    int nU = n * 64;   // u32 count of x
    k_cvt_x<<<(nU + 255) / 256, 256, 0, stream>>>(x, (uint32_t*)xbf, nU);
    cvt(lW1, W1b,  L * HD * HD);
    cvt(lW2, W2b,  L * HD * HD);
    cvt(Wih, Wib,  3 * HD * HD);
    cvt(Whh, Whb,  3 * HD * HD);
    cvt(fW1, fW1b, HD * HD);
    cvt(fW2, fW2b, 64 * HD);

    hipMemsetAsync(degB, 0, (size_t)n * 4, stream);
    hipMemsetAsync(hA, 0, (size_t)nPad * HD * 2, stream);

    k_bound<<<(n + 1 + 255) / 256, 256, 0, stream>>>(dst + E, E, rows2, n);
    k_count<<<(E + 255) / 256, 256, 0, stream>>>(dst, degB, E);
    int nb = (n + 1023) / 1024;
    k_scan1<<<nb, 256, 0, stream>>>(degB, rowsB, bsum, n);
    k_scan2<<<1, 128, 0, stream>>>(bsum, nb);
    k_scan3<<<(n + 1 + 255) / 256, 256, 0, stream>>>(rowsB, bsum, n, E);
    hipMemcpyAsync(curB, rowsB, (size_t)n * 4, hipMemcpyDeviceToDevice, stream);
    k_fill<<<(E + 255) / 256, 256, 0, stream>>>(src, dst, curB, colB, E);

    int nT128 = nPad / 128;
    int nT16 = (n + 15) / 16;
    int gF = (nT16 + NTPB - 1) / NTPB;

    const bf16* curp = xbf;
    for (int l = 0; l < L; ++l){
        k_gather<<<(n + 3) / 4, 256, 0, stream>>>(curp, src + E, rows2, colB, rowsB, cin, n);
        k_layer<<<256, 512, 0, stream>>>(cin, hA, hB,
            W1b + (size_t)l * HD * HD, lb1 + l * HD,
            W2b + (size_t)l * HD * HD, lb2 + l * HD,
            gmm + l * HD, bta + l * HD, mun + l * HD, vrr + l * HD,
            Wib, Whb, bih, bhh, nT128);
        bf16* tmp = hA; hA = hB; hB = tmp;
        curp = hA;
    }
    k_final<<<gF, 256, 0, stream>>>(hA, fW1b, fb1, fW2b, fb2, (float*)d_out, nT16);
}

// Round 7
// 821.751 us; speedup vs baseline: 1.3094x; 1.1303x over previous
//
#include <hip/hip_runtime.h>
#include <hip/hip_bf16.h>
#include <stdint.h>

typedef __bf16 bf16;
typedef __bf16 bf16x8 __attribute__((ext_vector_type(8)));
typedef float f32x4 __attribute__((ext_vector_type(4)));
typedef uint32_t u32x4 __attribute__((ext_vector_type(4)));

#define HD 128
#define LDP (HD + 8)
#define NTPB 4
#define MFMA __builtin_amdgcn_mfma_f32_16x16x32_bf16

__device__ inline float bflo(uint32_t u){ return __uint_as_float(u << 16); }
__device__ inline float bfhi(uint32_t u){ return __uint_as_float(u & 0xffff0000u); }
__device__ inline uint32_t packbf(float a, float b){
    bf16 x = (bf16)a, y = (bf16)b;
    uint16_t ux = __builtin_bit_cast(uint16_t, x), uy = __builtin_bit_cast(uint16_t, y);
    return (uint32_t)ux | ((uint32_t)uy << 16);
}
__device__ inline bf16x8 ldb8(const bf16* p){ return *(const bf16x8*)p; }
__device__ inline float sigm(float x){ return 1.f / (1.f + __expf(-x)); }
__device__ inline float tanh_fast(float x){ float t = __expf(-2.f * x); return (1.f - t) / (1.f + t); }
// 16B-slot swizzle within a 256B row: slot ^= row&7. Self-inverse.
__device__ inline uint32_t swz(uint32_t b){ return b ^ (((b >> 8) & 7u) << 4); }

// ---------------- weight conversion (plain) ----------------
__global__ void k_cvt(const float* __restrict__ in, bf16* __restrict__ out, int n){
    int i = blockIdx.x * 256 + threadIdx.x;
    if (i < n) out[i] = (bf16)in[i];
}

// ---------------- x conversion with per-row slot swizzle ----------------
__global__ void k_cvt_x(const float* __restrict__ in, uint32_t* __restrict__ out, int nU){
    int i = blockIdx.x * 256 + threadIdx.x;   // u32 index (2 bf16)
    if (i >= nU) return;
    int r = i >> 6, dw = i & 63;
    uint32_t v = packbf(in[(size_t)i * 2], in[(size_t)i * 2 + 1]);
    int slot = dw >> 2, w = dw & 3;
    out[(size_t)r * 64 + (((slot ^ (r & 7)) << 2) | w)] = v;
}

// ---------------- CSR (only the unsorted half needs building) ----------------
__global__ void k_bound(const int* __restrict__ dstB, int E, int* __restrict__ rows2, int n){
    int v = blockIdx.x * 256 + threadIdx.x;
    if (v > n) return;
    int lo = 0, hi = E;
    while (lo < hi){ int mid = (lo + hi) >> 1; if (dstB[mid] < v) lo = mid + 1; else hi = mid; }
    rows2[v] = lo;
}

__global__ void k_count(const int* __restrict__ dst, int* __restrict__ deg, int ne){
    int i = blockIdx.x * 256 + threadIdx.x;
    if (i < ne) atomicAdd(&deg[dst[i]], 1);
}

__global__ void k_scan1(const int* __restrict__ deg, int* __restrict__ rows,
                        int* __restrict__ bsum, int n){
    __shared__ int lds[256];
    int b = blockIdx.x, tid = threadIdx.x;
    int i0 = b * 1024 + tid * 4;
    int v[4]; int s = 0;
#pragma unroll
    for (int j = 0; j < 4; ++j){ int idx = i0 + j; v[j] = (idx < n) ? deg[idx] : 0; s += v[j]; }
    lds[tid] = s; __syncthreads();
    int acc = s;
    for (int off = 1; off < 256; off <<= 1){
        int add = (tid >= off) ? lds[tid - off] : 0;
        __syncthreads();
        acc += add; lds[tid] = acc;
        __syncthreads();
    }
    int run = acc - s;
#pragma unroll
    for (int j = 0; j < 4; ++j){ int idx = i0 + j; if (idx < n) rows[idx] = run; run += v[j]; }
    if (tid == 255) bsum[b] = acc;
}

__global__ void k_scan2(int* __restrict__ bsum, int nb){
    __shared__ int lds[128];
    int tid = threadIdx.x;
    int v = (tid < nb) ? bsum[tid] : 0;
    lds[tid] = v; __syncthreads();
    int acc = v;
    for (int off = 1; off < 128; off <<= 1){
        int add = (tid >= off) ? lds[tid - off] : 0;
        __syncthreads();
        acc += add; lds[tid] = acc;
        __syncthreads();
    }
    if (tid < nb) bsum[tid] = acc - v;
}

__global__ void k_scan3(int* __restrict__ rows, const int* __restrict__ bsum, int n, int total){
    int i = blockIdx.x * 256 + threadIdx.x;
    if (i < n) rows[i] += bsum[i >> 10];
    if (i == n) rows[n] = total;
}

__global__ void k_fill(const int* __restrict__ src, const int* __restrict__ dst,
                       int* __restrict__ cur, int* __restrict__ col, int ne){
    int i = blockIdx.x * 256 + threadIdx.x;
    if (i < ne){ int p = atomicAdd(&cur[dst[i]], 1); col[p] = src[i]; }
}

// ---------------- mean aggregation over swizzled rows ----------------
__global__ __launch_bounds__(256) void k_gather(
    const bf16* __restrict__ curx,
    const int* __restrict__ srcB, const int* __restrict__ rows2,
    const int* __restrict__ colB, const int* __restrict__ rowsB,
    bf16* __restrict__ cout, int n)
{
    int wid = threadIdx.x >> 6, lane = threadIdx.x & 63;
    int v = blockIdx.x * 4 + wid;
    if (v >= n) return;
    int grp = lane >> 3, sl = lane & 7;
    int a0 = rows2[v], a1 = rows2[v + 1];
    int b0 = rowsB[v], b1 = rowsB[v + 1];
    int deg = (a1 - a0) + (b1 - b0);
    float inv = (deg > 0) ? 1.f / (float)deg : 0.f;

    const u32x4* base = (const u32x4*)curx;
    float acc[16];
#pragma unroll
    for (int k = 0; k < 16; ++k) acc[k] = 0.f;

    for (int j = a0 + grp; j < a1; j += 8){
        int nb = srcB[j];
        int px = nb & 7;
        u32x4 q0 = base[(size_t)nb * 16 + (sl ^ px)];
        u32x4 q1 = base[(size_t)nb * 16 + 8 + (sl ^ px)];
#pragma unroll
        for (int k = 0; k < 4; ++k){
            acc[2*k]   += bflo(q0[k]); acc[2*k+1]   += bfhi(q0[k]);
            acc[8+2*k] += bflo(q1[k]); acc[8+2*k+1] += bfhi(q1[k]);
        }
    }
    for (int j = b0 + grp; j < b1; j += 8){
        int nb = colB[j];
        int px = nb & 7;
        u32x4 q0 = base[(size_t)nb * 16 + (sl ^ px)];
        u32x4 q1 = base[(size_t)nb * 16 + 8 + (sl ^ px)];
#pragma unroll
        for (int k = 0; k < 4; ++k){
            acc[2*k]   += bflo(q0[k]); acc[2*k+1]   += bfhi(q0[k]);
            acc[8+2*k] += bflo(q1[k]); acc[8+2*k+1] += bfhi(q1[k]);
        }
    }
#pragma unroll
    for (int k = 0; k < 16; ++k){
        acc[k] += __shfl_xor(acc[k], 8);
        acc[k] += __shfl_xor(acc[k], 16);
        acc[k] += __shfl_xor(acc[k], 32);
    }
    if (grp == 0){
        int pv = v & 7;
        u32x4 x0 = base[(size_t)v * 16 + (sl ^ pv)];
        u32x4 x1 = base[(size_t)v * 16 + 8 + (sl ^ pv)];
        u32x4 o0, o1;
#pragma unroll
        for (int k = 0; k < 4; ++k){
            o0[k] = packbf(bflo(x0[k]) + acc[2*k] * inv,   bfhi(x0[k]) + acc[2*k+1] * inv);
            o1[k] = packbf(bflo(x1[k]) + acc[8+2*k] * inv, bfhi(x1[k]) + acc[8+2*k+1] * inv);
        }
        ((u32x4*)cout)[(size_t)v * 16 + (sl ^ pv)]     = o0;
        ((u32x4*)cout)[(size_t)v * 16 + 8 + (sl ^ pv)] = o1;
    }
}

// ---------------- fused Layer: wave-stationary weights, async LDS activation tiles ----
// 512 thr = 8 waves; wave w owns output cols w*16..w*16+15 for MLP and all 3 GRU gates.
// LDS 128KB: c-tile dbuf (2x32K) + h-tile (32K) + act1 (32K, reused as hNew staging).
// hNew goes LDS -> coalesced dwordx4 copy-out (no partial-line RMW scatter stores).
#define CL0 0u
#define CL1 32768u
#define HL0 65536u
#define ALO 98304u
__global__ __launch_bounds__(512, 2) void k_layer(
    const bf16* __restrict__ cin, const bf16* __restrict__ hOld, bf16* __restrict__ hNew,
    const bf16* __restrict__ W1, const float* __restrict__ b1,
    const bf16* __restrict__ W2, const float* __restrict__ b2,
    const float* __restrict__ gm, const float* __restrict__ bt,
    const float* __restrict__ mu, const float* __restrict__ vr,
    const bf16* __restrict__ Wih, const bf16* __restrict__ Whh,
    const float* __restrict__ bih, const float* __restrict__ bhh, int nT)
{
    __shared__ __align__(16) char smem[131072];
    int tid = threadIdx.x, wid = tid >> 6, lane = tid & 63;
    int rA = lane & 15, u = lane >> 4, ko = u * 8;
    int c = wid * 16 + rA;                       // this lane's output column

    // ---- weights -> registers (once per block) ----
    bf16x8 W1f[4], W2f[4], Gri[4], Grh[4], Gzi[4], Gzh[4], Gni[4], Gnh[4];
#pragma unroll
    for (int kk = 0; kk < 4; ++kk){
        W1f[kk] = ldb8(W1  + (size_t)c * HD + ko + kk * 32);
        W2f[kk] = ldb8(W2  + (size_t)c * HD + ko + kk * 32);
        Gri[kk] = ldb8(Wih + (size_t)c * HD + ko + kk * 32);
        Gzi[kk] = ldb8(Wih + (size_t)(c + 128) * HD + ko + kk * 32);
        Gni[kk] = ldb8(Wih + (size_t)(c + 256) * HD + ko + kk * 32);
        Grh[kk] = ldb8(Whh + (size_t)c * HD + ko + kk * 32);
        Gzh[kk] = ldb8(Whh + (size_t)(c + 128) * HD + ko + kk * 32);
        Gnh[kk] = ldb8(Whh + (size_t)(c + 256) * HD + ko + kk * 32);
    }
    float b1c = b1[c];
    float bnS = gm[c] * rsqrtf(vr[c] + 1e-5f);
    float bnO = bt[c] - mu[c] * bnS;
    float b2c = b2[c];
    float br = bih[c] + bhh[c], bz = bih[c + 128] + bhh[c + 128];
    float bin = bih[c + 256], bhn = bhh[c + 256];

    auto gload = [&](const char* g, uint32_t lo){
        __builtin_amdgcn_global_load_lds(
            (const __attribute__((address_space(1))) void*)g,
            (__attribute__((address_space(3))) void*)(smem + lo), 16, 0, 0);
    };
    auto stageC = [&](int t, uint32_t dst){
        const char* g = (const char*)cin + (size_t)t * 32768 + (size_t)lane * 16;
#pragma unroll
        for (int i = 0; i < 4; ++i){
            uint32_t ch = (uint32_t)(wid * 4 + i) * 1024;
            gload(g + ch, dst + ch);
        }
    };
    auto stageH = [&](int t){
        const char* g = (const char*)hOld + (size_t)t * 32768 + (size_t)lane * 16;
#pragma unroll
        for (int i = 0; i < 4; ++i){
            uint32_t ch = (uint32_t)(wid * 4 + i) * 1024;
            gload(g + ch, HL0 + ch);
        }
    };

    int t = blockIdx.x;
    int cur = 0;
    if (t < nT) stageC(t, CL0);
    for (; t < nT; t += (int)gridDim.x){
        __syncthreads();                          // drains stage of c(t) (+ prior stores)
        stageH(t);                                // 4 issues (oldest)
        int tn = t + (int)gridDim.x;
        if (tn < nT) stageC(tn, cur ? CL0 : CL1); // 4 issues (newest, fly all tile)
        uint32_t CB = cur ? CL1 : CL0;

        // ---- GEMM1 + ReLU -> act1 ----
#pragma unroll
        for (int m = 0; m < 8; ++m){
            bf16x8 a_[4];
#pragma unroll
            for (int kk = 0; kk < 4; ++kk){
                uint32_t b = (uint32_t)(m * 16 + rA) * 256 + (uint32_t)(u * 16 + kk * 64);
                a_[kk] = *(const bf16x8*)(smem + CB + swz(b));
            }
            f32x4 acc = {0,0,0,0};
#pragma unroll
            for (int kk = 0; kk < 4; ++kk) acc = MFMA(a_[kk], W1f[kk], acc, 0, 0, 0);
#pragma unroll
            for (int j = 0; j < 4; ++j){
                uint32_t r = (uint32_t)(m * 16 + u * 4 + j);
                *(bf16*)(smem + ALO + swz(r * 256 + (uint32_t)c * 2)) =
                    (bf16)fmaxf(acc[j] + b1c, 0.f);
            }
        }
        asm volatile("s_waitcnt lgkmcnt(0)" ::: "memory");
        __builtin_amdgcn_sched_barrier(0);
        __builtin_amdgcn_s_barrier();

        // ---- GEMM2 + BN -> c-tile (overwrites consumed cin) ----
#pragma unroll
        for (int m = 0; m < 8; ++m){
            bf16x8 a_[4];
#pragma unroll
            for (int kk = 0; kk < 4; ++kk){
                uint32_t b = (uint32_t)(m * 16 + rA) * 256 + (uint32_t)(u * 16 + kk * 64);
                a_[kk] = *(const bf16x8*)(smem + ALO + swz(b));
            }
            f32x4 acc = {0,0,0,0};
#pragma unroll
            for (int kk = 0; kk < 4; ++kk) acc = MFMA(a_[kk], W2f[kk], acc, 0, 0, 0);
#pragma unroll
            for (int j = 0; j < 4; ++j){
                uint32_t r = (uint32_t)(m * 16 + u * 4 + j);
                *(bf16*)(smem + CB + swz(r * 256 + (uint32_t)c * 2)) =
                    (bf16)((acc[j] + b2c) * bnS + bnO);
            }
        }
        // h(t) must be landed (4 oldest); c(t+1) may stay in flight (4 newest)
        if (tn < nT){ asm volatile("s_waitcnt vmcnt(4) lgkmcnt(0)" ::: "memory"); }
        else        { asm volatile("s_waitcnt vmcnt(0) lgkmcnt(0)" ::: "memory"); }
        __builtin_amdgcn_sched_barrier(0);
        __builtin_amdgcn_s_barrier();

        // ---- GRU: outputs staged into ALO (act1 is dead after GEMM2) ----
#pragma unroll
        for (int m = 0; m < 8; ++m){
            bf16x8 ac_[4], ah_[4];
#pragma unroll
            for (int kk = 0; kk < 4; ++kk){
                uint32_t b = (uint32_t)(m * 16 + rA) * 256 + (uint32_t)(u * 16 + kk * 64);
                ac_[kk] = *(const bf16x8*)(smem + CB + swz(b));
                ah_[kk] = *(const bf16x8*)(smem + HL0 + swz(b));
            }
            f32x4 rr = {0,0,0,0}, zz = {0,0,0,0}, gi = {0,0,0,0}, gh = {0,0,0,0};
#pragma unroll
            for (int kk = 0; kk < 4; ++kk){
                rr = MFMA(ac_[kk], Gri[kk], rr, 0, 0, 0);
                rr = MFMA(ah_[kk], Grh[kk], rr, 0, 0, 0);
                zz = MFMA(ac_[kk], Gzi[kk], zz, 0, 0, 0);
                zz = MFMA(ah_[kk], Gzh[kk], zz, 0, 0, 0);
                gi = MFMA(ac_[kk], Gni[kk], gi, 0, 0, 0);
                gh = MFMA(ah_[kk], Gnh[kk], gh, 0, 0, 0);
            }
#pragma unroll
            for (int j = 0; j < 4; ++j){
                uint32_t r = (uint32_t)(m * 16 + u * 4 + j);
                uint32_t inner = swz(r * 256 + (uint32_t)c * 2);
                float hold = (float)*(const bf16*)(smem + HL0 + inner);
                float rg = sigm(rr[j] + br);
                float zg = sigm(zz[j] + bz);
                float ng = tanh_fast(gi[j] + bin + rg * (gh[j] + bhn));
                *(bf16*)(smem + ALO + inner) = (bf16)((1.f - zg) * ng + zg * hold);
            }
        }
        asm volatile("s_waitcnt lgkmcnt(0)" ::: "memory");
        __builtin_amdgcn_sched_barrier(0);
        __builtin_amdgcn_s_barrier();

        // ---- coalesced copy-out: ALO -> hNew (full-line dwordx4 stores) ----
        {
            char* hNb = (char*)hNew + (size_t)t * 32768;
#pragma unroll
            for (int i = 0; i < 4; ++i){
                uint32_t off = (uint32_t)tid * 16 + (uint32_t)i * 8192;
                *(u32x4*)(hNb + off) = *(const u32x4*)(smem + ALO + off);
            }
        }
        cur ^= 1;
    }
}

// ---------------- final MLP: 128 -> 128 (ReLU) -> 64, f32 out ----------------
__global__ __launch_bounds__(256) void k_final(
    const bf16* __restrict__ hin, const bf16* __restrict__ W1, const float* __restrict__ b1,
    const bf16* __restrict__ W2, const float* __restrict__ b2,
    float* __restrict__ out, int nTiles)
{
    __shared__ bf16 lds[NTPB][16][LDP];
    int wid = threadIdx.x >> 6, lane = threadIdx.x & 63;
    int tile = blockIdx.x * NTPB + wid;
    if (tile >= nTiles) return;
    int r0 = tile * 16;
    int rA = lane & 15, u = lane >> 4, ko = u * 8;

    // hin rows are slot-swizzled
    bf16x8 a[4];
    const char* hb = (const char*)hin;
    uint32_t b0 = (uint32_t)(r0 + rA) * 256 + (uint32_t)(u * 16);
#pragma unroll
    for (int kk = 0; kk < 4; ++kk) a[kk] = *(const bf16x8*)(hb + swz(b0 + (uint32_t)kk * 64));

#pragma unroll
    for (int t = 0; t < 8; ++t){
        f32x4 acc = {0.f, 0.f, 0.f, 0.f};
        int c = t * 16 + rA;
        const bf16* bp = W1 + (size_t)c * HD + ko;
#pragma unroll
        for (int kk = 0; kk < 4; ++kk)
            acc = MFMA(a[kk], ldb8(bp + kk * 32), acc, 0, 0, 0);
        float bias = b1[c];
#pragma unroll
        for (int j = 0; j < 4; ++j){
            float v = fmaxf(acc[j] + bias, 0.f);
            lds[wid][u * 4 + j][c] = (bf16)v;
        }
    }
    __threadfence_block();
    bf16x8 a2[4];
    const bf16* lp = &lds[wid][rA][ko];
#pragma unroll
    for (int kk = 0; kk < 4; ++kk) a2[kk] = ldb8(lp + kk * 32);

#pragma unroll
    for (int t = 0; t < 4; ++t){
        f32x4 acc = {0.f, 0.f, 0.f, 0.f};
        int c = t * 16 + rA;
        const bf16* bp = W2 + (size_t)c * HD + ko;
#pragma unroll
        for (int kk = 0; kk < 4; ++kk)
            acc = MFMA(a2[kk], ldb8(bp + kk * 32), acc, 0, 0, 0);
        float bias = b2[c];
#pragma unroll
        for (int j = 0; j < 4; ++j)
            out[(size_t)(r0 + u * 4 + j) * 64 + c] = acc[j] + bias;
    }
}

extern "C" void kernel_launch(void* const* d_in, const int* in_sizes, int n_in,
                              void* d_out, int out_size, void* d_ws, size_t ws_size,
                              hipStream_t stream)
{
    const float* x    = (const float*)d_in[0];
    const int*   src  = (const int*)d_in[1];
    const int*   dst  = (const int*)d_in[2];
    const float* lW1  = (const float*)d_in[3];
    const float* lb1  = (const float*)d_in[4];
    const float* lW2  = (const float*)d_in[5];
    const float* lb2  = (const float*)d_in[6];
    const float* gmm  = (const float*)d_in[7];
    const float* bta  = (const float*)d_in[8];
    const float* mun  = (const float*)d_in[9];
    const float* vrr  = (const float*)d_in[10];
    const float* Wih  = (const float*)d_in[11];
    const float* Whh  = (const float*)d_in[12];
    const float* bih  = (const float*)d_in[13];
    const float* bhh  = (const float*)d_in[14];
    const float* fW1  = (const float*)d_in[15];
    const float* fb1  = (const float*)d_in[16];
    const float* fW2  = (const float*)d_in[17];
    const float* fb2  = (const float*)d_in[18];

    int n  = in_sizes[0] / HD;
    int ne = in_sizes[1];
    int E  = ne / 2;                    // dst[E:2E) is sorted
    int L  = in_sizes[3] / (HD * HD);
    int nPad = (n + 127) & ~127;

    char* w = (char*)d_ws;
    auto alloc = [&](size_t bytes) -> char* {
        char* p = w; w += (bytes + 255) & ~(size_t)255; return p;
    };
    bf16* xbf  = (bf16*)alloc((size_t)nPad * HD * 2);
    bf16* hA   = (bf16*)alloc((size_t)nPad * HD * 2);
    bf16* hB   = (bf16*)alloc((size_t)nPad * HD * 2);
    bf16* cin  = (bf16*)alloc((size_t)nPad * HD * 2);
    bf16* W1b  = (bf16*)alloc((size_t)L * HD * HD * 2);
    bf16* W2b  = (bf16*)alloc((size_t)L * HD * HD * 2);
    bf16* Wib  = (bf16*)alloc((size_t)3 * HD * HD * 2);
    bf16* Whb  = (bf16*)alloc((size_t)3 * HD * HD * 2);
    bf16* fW1b = (bf16*)alloc((size_t)HD * HD * 2);
    bf16* fW2b = (bf16*)alloc((size_t)64 * HD * 2);
    int*  degB = (int*)alloc((size_t)n * 4);
    int*  rowsB= (int*)alloc((size_t)(n + 1) * 4);
    int*  rows2= (int*)alloc((size_t)(n + 1) * 4);
    int*  bsum = (int*)alloc(512);
    int*  curB = (int*)alloc((size_t)n * 4);
    int*  colB = (int*)alloc((size_t)E * 4);

    auto cvt = [&](const float* i, bf16* o, int cnt){
        k_cvt<<<(cnt + 255) / 256, 256, 0, stream>>>(i, o, cnt);
    };
    int nU = n * 64;   // u32 count of x
    k_cvt_x<<<(nU + 255) / 256, 256, 0, stream>>>(x, (uint32_t*)xbf, nU);
    cvt(lW1, W1b,  L * HD * HD);
    cvt(lW2, W2b,  L * HD * HD);
    cvt(Wih, Wib,  3 * HD * HD);
    cvt(Whh, Whb,  3 * HD * HD);
    cvt(fW1, fW1b, HD * HD);
    cvt(fW2, fW2b, 64 * HD);

    hipMemsetAsync(degB, 0, (size_t)n * 4, stream);
    hipMemsetAsync(hA, 0, (size_t)nPad * HD * 2, stream);

    k_bound<<<(n + 1 + 255) / 256, 256, 0, stream>>>(dst + E, E, rows2, n);
    k_count<<<(E + 255) / 256, 256, 0, stream>>>(dst, degB, E);
    int nb = (n + 1023) / 1024;
    k_scan1<<<nb, 256, 0, stream>>>(degB, rowsB, bsum, n);
    k_scan2<<<1, 128, 0, stream>>>(bsum, nb);
    k_scan3<<<(n + 1 + 255) / 256, 256, 0, stream>>>(rowsB, bsum, n, E);
    hipMemcpyAsync(curB, rowsB, (size_t)n * 4, hipMemcpyDeviceToDevice, stream);
    k_fill<<<(E + 255) / 256, 256, 0, stream>>>(src, dst, curB, colB, E);

    int nT128 = nPad / 128;
    int nT16 = (n + 15) / 16;
    int gF = (nT16 + NTPB - 1) / NTPB;

    const bf16* curp = xbf;
    for (int l = 0; l < L; ++l){
        k_gather<<<(n + 3) / 4, 256, 0, stream>>>(curp, src + E, rows2, colB, rowsB, cin, n);
        k_layer<<<256, 512, 0, stream>>>(cin, hA, hB,
            W1b + (size_t)l * HD * HD, lb1 + l * HD,
            W2b + (size_t)l * HD * HD, lb2 + l * HD,
            gmm + l * HD, bta + l * HD, mun + l * HD, vrr + l * HD,
            Wib, Whb, bih, bhh, nT128);
        bf16* tmp = hA; hA = hB; hB = tmp;
        curp = hA;
    }
    k_final<<<gF, 256, 0, stream>>>(hA, fW1b, fb1, fW2b, fb2, (float*)d_out, nT16);
}

// Round 8
// 764.262 us; speedup vs baseline: 1.4078x; 1.0752x over previous
//
#include <hip/hip_runtime.h>
#include <hip/hip_bf16.h>
#include <stdint.h>

typedef __bf16 bf16;
typedef __bf16 bf16x8 __attribute__((ext_vector_type(8)));
typedef float f32x4 __attribute__((ext_vector_type(4)));
typedef uint32_t u32x4 __attribute__((ext_vector_type(4)));

#define HD 128
#define LDP (HD + 8)
#define NTPB 4
#define MFMA __builtin_amdgcn_mfma_f32_16x16x32_bf16

__device__ inline float bflo(uint32_t u){ return __uint_as_float(u << 16); }
__device__ inline float bfhi(uint32_t u){ return __uint_as_float(u & 0xffff0000u); }
__device__ inline uint32_t packbf(float a, float b){
    bf16 x = (bf16)a, y = (bf16)b;
    uint16_t ux = __builtin_bit_cast(uint16_t, x), uy = __builtin_bit_cast(uint16_t, y);
    return (uint32_t)ux | ((uint32_t)uy << 16);
}
__device__ inline bf16x8 ldb8(const bf16* p){ return *(const bf16x8*)p; }
__device__ inline float sigm(float x){ return 1.f / (1.f + __expf(-x)); }
__device__ inline float tanh_fast(float x){ float t = __expf(-2.f * x); return (1.f - t) / (1.f + t); }
// 16B-slot swizzle within a 256B row: slot ^= row&7. Self-inverse.
__device__ inline uint32_t swz(uint32_t b){ return b ^ (((b >> 8) & 7u) << 4); }

// ---------------- weight conversion (plain) ----------------
__global__ void k_cvt(const float* __restrict__ in, bf16* __restrict__ out, int n){
    int i = blockIdx.x * 256 + threadIdx.x;
    if (i < n) out[i] = (bf16)in[i];
}

// ---------------- x conversion with per-row slot swizzle ----------------
__global__ void k_cvt_x(const float* __restrict__ in, uint32_t* __restrict__ out, int nU){
    int i = blockIdx.x * 256 + threadIdx.x;   // u32 index (2 bf16)
    if (i >= nU) return;
    int r = i >> 6, dw = i & 63;
    uint32_t v = packbf(in[(size_t)i * 2], in[(size_t)i * 2 + 1]);
    int slot = dw >> 2, w = dw & 3;
    out[(size_t)r * 64 + (((slot ^ (r & 7)) << 2) | w)] = v;
}

// ---------------- CSR (only the unsorted half needs building) ----------------
__global__ void k_bound(const int* __restrict__ dstB, int E, int* __restrict__ rows2, int n){
    int v = blockIdx.x * 256 + threadIdx.x;
    if (v > n) return;
    int lo = 0, hi = E;
    while (lo < hi){ int mid = (lo + hi) >> 1; if (dstB[mid] < v) lo = mid + 1; else hi = mid; }
    rows2[v] = lo;
}

__global__ void k_count(const int* __restrict__ dst, int* __restrict__ deg, int ne){
    int i = blockIdx.x * 256 + threadIdx.x;
    if (i < ne) atomicAdd(&deg[dst[i]], 1);
}

__global__ void k_scan1(const int* __restrict__ deg, int* __restrict__ rows,
                        int* __restrict__ bsum, int n){
    __shared__ int lds[256];
    int b = blockIdx.x, tid = threadIdx.x;
    int i0 = b * 1024 + tid * 4;
    int v[4]; int s = 0;
#pragma unroll
    for (int j = 0; j < 4; ++j){ int idx = i0 + j; v[j] = (idx < n) ? deg[idx] : 0; s += v[j]; }
    lds[tid] = s; __syncthreads();
    int acc = s;
    for (int off = 1; off < 256; off <<= 1){
        int add = (tid >= off) ? lds[tid - off] : 0;
        __syncthreads();
        acc += add; lds[tid] = acc;
        __syncthreads();
    }
    int run = acc - s;
#pragma unroll
    for (int j = 0; j < 4; ++j){ int idx = i0 + j; if (idx < n) rows[idx] = run; run += v[j]; }
    if (tid == 255) bsum[b] = acc;
}

__global__ void k_scan2(int* __restrict__ bsum, int nb){
    __shared__ int lds[128];
    int tid = threadIdx.x;
    int v = (tid < nb) ? bsum[tid] : 0;
    lds[tid] = v; __syncthreads();
    int acc = v;
    for (int off = 1; off < 128; off <<= 1){
        int add = (tid >= off) ? lds[tid - off] : 0;
        __syncthreads();
        acc += add; lds[tid] = acc;
        __syncthreads();
    }
    if (tid < nb) bsum[tid] = acc - v;
}

__global__ void k_scan3(int* __restrict__ rows, const int* __restrict__ bsum, int n, int total){
    int i = blockIdx.x * 256 + threadIdx.x;
    if (i < n) rows[i] += bsum[i >> 10];
    if (i == n) rows[n] = total;
}

// XCD-partitioned fill: group g (= blockIdx&7, round-robin -> one XCD) commits only
// edges whose dst lies in node-slice g, so every col/cur cache line is written by a
// single XCD's L2 -> partial stores merge instead of 64B-per-store writebacks.
__global__ void k_fillp(const int* __restrict__ src, const int* __restrict__ dst,
                        int* __restrict__ cur, int* __restrict__ col, int ne, int nPerG){
    int g = blockIdx.x & 7;
    int i = (blockIdx.x >> 3) * 256 + threadIdx.x;
    if (i >= ne) return;
    int d = dst[i];
    int lo = g * nPerG;
    if (d >= lo && d < lo + nPerG){
        int p = atomicAdd(&cur[d], 1);
        col[p] = src[i];
    }
}

// ---------------- mean aggregation over swizzled rows ----------------
__global__ __launch_bounds__(256) void k_gather(
    const bf16* __restrict__ curx,
    const int* __restrict__ srcB, const int* __restrict__ rows2,
    const int* __restrict__ colB, const int* __restrict__ rowsB,
    bf16* __restrict__ cout, int n)
{
    int wid = threadIdx.x >> 6, lane = threadIdx.x & 63;
    int v = blockIdx.x * 4 + wid;
    if (v >= n) return;
    int grp = lane >> 3, sl = lane & 7;
    int a0 = rows2[v], a1 = rows2[v + 1];
    int b0 = rowsB[v], b1 = rowsB[v + 1];
    int deg = (a1 - a0) + (b1 - b0);
    float inv = (deg > 0) ? 1.f / (float)deg : 0.f;

    const u32x4* base = (const u32x4*)curx;
    float acc[16];
#pragma unroll
    for (int k = 0; k < 16; ++k) acc[k] = 0.f;

    for (int j = a0 + grp; j < a1; j += 8){
        int nb = srcB[j];
        int px = nb & 7;
        u32x4 q0 = base[(size_t)nb * 16 + (sl ^ px)];
        u32x4 q1 = base[(size_t)nb * 16 + 8 + (sl ^ px)];
#pragma unroll
        for (int k = 0; k < 4; ++k){
            acc[2*k]   += bflo(q0[k]); acc[2*k+1]   += bfhi(q0[k]);
            acc[8+2*k] += bflo(q1[k]); acc[8+2*k+1] += bfhi(q1[k]);
        }
    }
    for (int j = b0 + grp; j < b1; j += 8){
        int nb = colB[j];
        int px = nb & 7;
        u32x4 q0 = base[(size_t)nb * 16 + (sl ^ px)];
        u32x4 q1 = base[(size_t)nb * 16 + 8 + (sl ^ px)];
#pragma unroll
        for (int k = 0; k < 4; ++k){
            acc[2*k]   += bflo(q0[k]); acc[2*k+1]   += bfhi(q0[k]);
            acc[8+2*k] += bflo(q1[k]); acc[8+2*k+1] += bfhi(q1[k]);
        }
    }
#pragma unroll
    for (int k = 0; k < 16; ++k){
        acc[k] += __shfl_xor(acc[k], 8);
        acc[k] += __shfl_xor(acc[k], 16);
        acc[k] += __shfl_xor(acc[k], 32);
    }
    if (grp == 0){
        int pv = v & 7;
        u32x4 x0 = base[(size_t)v * 16 + (sl ^ pv)];
        u32x4 x1 = base[(size_t)v * 16 + 8 + (sl ^ pv)];
        u32x4 o0, o1;
#pragma unroll
        for (int k = 0; k < 4; ++k){
            o0[k] = packbf(bflo(x0[k]) + acc[2*k] * inv,   bfhi(x0[k]) + acc[2*k+1] * inv);
            o1[k] = packbf(bflo(x1[k]) + acc[8+2*k] * inv, bfhi(x1[k]) + acc[8+2*k+1] * inv);
        }
        ((u32x4*)cout)[(size_t)v * 16 + (sl ^ pv)]     = o0;
        ((u32x4*)cout)[(size_t)v * 16 + 8 + (sl ^ pv)] = o1;
    }
}

// ---------------- fused Layer: wave-stationary weights, async LDS activation tiles ----
// 512 thr = 8 waves; wave w owns output cols w*16..w*16+15 for MLP and all 3 GRU gates.
// LDS 128KB (1 block/CU): c dbuf (2x32K) + h (32K) + act1/hNew staging (32K).
// __launch_bounds__(512,1): allow ~240 VGPR so the 128 weight VGPRs stay RESIDENT
// (r6/r7 ran at VGPR_Count=128 -> compiler was re-loading weights every tile).
#define CL0 0u
#define CL1 32768u
#define HL0 65536u
#define ALO 98304u
__global__ __launch_bounds__(512, 1) void k_layer(
    const bf16* __restrict__ cin, const bf16* __restrict__ hOld, bf16* __restrict__ hNew,
    const bf16* __restrict__ W1, const float* __restrict__ b1,
    const bf16* __restrict__ W2, const float* __restrict__ b2,
    const float* __restrict__ gm, const float* __restrict__ bt,
    const float* __restrict__ mu, const float* __restrict__ vr,
    const bf16* __restrict__ Wih, const bf16* __restrict__ Whh,
    const float* __restrict__ bih, const float* __restrict__ bhh, int nT)
{
    __shared__ __align__(16) char smem[131072];
    int tid = threadIdx.x, wid = tid >> 6, lane = tid & 63;
    int rA = lane & 15, u = lane >> 4, ko = u * 8;
    int c = wid * 16 + rA;                       // this lane's output column

    // ---- weights -> registers (once per block) ----
    bf16x8 W1f[4], W2f[4], Gri[4], Grh[4], Gzi[4], Gzh[4], Gni[4], Gnh[4];
#pragma unroll
    for (int kk = 0; kk < 4; ++kk){
        W1f[kk] = ldb8(W1  + (size_t)c * HD + ko + kk * 32);
        W2f[kk] = ldb8(W2  + (size_t)c * HD + ko + kk * 32);
        Gri[kk] = ldb8(Wih + (size_t)c * HD + ko + kk * 32);
        Gzi[kk] = ldb8(Wih + (size_t)(c + 128) * HD + ko + kk * 32);
        Gni[kk] = ldb8(Wih + (size_t)(c + 256) * HD + ko + kk * 32);
        Grh[kk] = ldb8(Whh + (size_t)c * HD + ko + kk * 32);
        Gzh[kk] = ldb8(Whh + (size_t)(c + 128) * HD + ko + kk * 32);
        Gnh[kk] = ldb8(Whh + (size_t)(c + 256) * HD + ko + kk * 32);
    }
    float b1c = b1[c];
    float bnS = gm[c] * rsqrtf(vr[c] + 1e-5f);
    float bnO = bt[c] - mu[c] * bnS;
    float b2c = b2[c];
    float br = bih[c] + bhh[c], bz = bih[c + 128] + bhh[c + 128];
    float bin = bih[c + 256], bhn = bhh[c + 256];

    auto gload = [&](const char* g, uint32_t lo){
        __builtin_amdgcn_global_load_lds(
            (const __attribute__((address_space(1))) void*)g,
            (__attribute__((address_space(3))) void*)(smem + lo), 16, 0, 0);
    };
    auto stageC = [&](int t, uint32_t dst){
        const char* g = (const char*)cin + (size_t)t * 32768 + (size_t)lane * 16;
#pragma unroll
        for (int i = 0; i < 4; ++i){
            uint32_t ch = (uint32_t)(wid * 4 + i) * 1024;
            gload(g + ch, dst + ch);
        }
    };
    auto stageH = [&](int t){
        const char* g = (const char*)hOld + (size_t)t * 32768 + (size_t)lane * 16;
#pragma unroll
        for (int i = 0; i < 4; ++i){
            uint32_t ch = (uint32_t)(wid * 4 + i) * 1024;
            gload(g + ch, HL0 + ch);
        }
    };

    int t = blockIdx.x;
    int cur = 0;
    if (t < nT) stageC(t, CL0);
    for (; t < nT; t += (int)gridDim.x){
        __syncthreads();                          // drains stage of c(t) (+ prior stores)
        stageH(t);                                // 4 issues (oldest)
        int tn = t + (int)gridDim.x;
        if (tn < nT) stageC(tn, cur ? CL0 : CL1); // 4 issues (newest, fly all tile)
        uint32_t CB = cur ? CL1 : CL0;

        // ---- GEMM1 + ReLU -> act1 ----
#pragma unroll
        for (int m = 0; m < 8; ++m){
            bf16x8 a_[4];
#pragma unroll
            for (int kk = 0; kk < 4; ++kk){
                uint32_t b = (uint32_t)(m * 16 + rA) * 256 + (uint32_t)(u * 16 + kk * 64);
                a_[kk] = *(const bf16x8*)(smem + CB + swz(b));
            }
            f32x4 acc = {0,0,0,0};
#pragma unroll
            for (int kk = 0; kk < 4; ++kk) acc = MFMA(a_[kk], W1f[kk], acc, 0, 0, 0);
#pragma unroll
            for (int j = 0; j < 4; ++j){
                uint32_t r = (uint32_t)(m * 16 + u * 4 + j);
                *(bf16*)(smem + ALO + swz(r * 256 + (uint32_t)c * 2)) =
                    (bf16)fmaxf(acc[j] + b1c, 0.f);
            }
        }
        asm volatile("s_waitcnt lgkmcnt(0)" ::: "memory");
        __builtin_amdgcn_sched_barrier(0);
        __builtin_amdgcn_s_barrier();

        // ---- GEMM2 + BN -> c-tile (overwrites consumed cin) ----
#pragma unroll
        for (int m = 0; m < 8; ++m){
            bf16x8 a_[4];
#pragma unroll
            for (int kk = 0; kk < 4; ++kk){
                uint32_t b = (uint32_t)(m * 16 + rA) * 256 + (uint32_t)(u * 16 + kk * 64);
                a_[kk] = *(const bf16x8*)(smem + ALO + swz(b));
            }
            f32x4 acc = {0,0,0,0};
#pragma unroll
            for (int kk = 0; kk < 4; ++kk) acc = MFMA(a_[kk], W2f[kk], acc, 0, 0, 0);
#pragma unroll
            for (int j = 0; j < 4; ++j){
                uint32_t r = (uint32_t)(m * 16 + u * 4 + j);
                *(bf16*)(smem + CB + swz(r * 256 + (uint32_t)c * 2)) =
                    (bf16)((acc[j] + b2c) * bnS + bnO);
            }
        }
        // h(t) must be landed (4 oldest); c(t+1) may stay in flight (4 newest)
        if (tn < nT){ asm volatile("s_waitcnt vmcnt(4) lgkmcnt(0)" ::: "memory"); }
        else        { asm volatile("s_waitcnt vmcnt(0) lgkmcnt(0)" ::: "memory"); }
        __builtin_amdgcn_sched_barrier(0);
        __builtin_amdgcn_s_barrier();

        // ---- GRU: outputs staged into ALO (act1 is dead after GEMM2) ----
#pragma unroll
        for (int m = 0; m < 8; ++m){
            bf16x8 ac_[4], ah_[4];
#pragma unroll
            for (int kk = 0; kk < 4; ++kk){
                uint32_t b = (uint32_t)(m * 16 + rA) * 256 + (uint32_t)(u * 16 + kk * 64);
                ac_[kk] = *(const bf16x8*)(smem + CB + swz(b));
                ah_[kk] = *(const bf16x8*)(smem + HL0 + swz(b));
            }
            f32x4 rr = {0,0,0,0}, zz = {0,0,0,0}, gi = {0,0,0,0}, gh = {0,0,0,0};
#pragma unroll
            for (int kk = 0; kk < 4; ++kk){
                rr = MFMA(ac_[kk], Gri[kk], rr, 0, 0, 0);
                rr = MFMA(ah_[kk], Grh[kk], rr, 0, 0, 0);
                zz = MFMA(ac_[kk], Gzi[kk], zz, 0, 0, 0);
                zz = MFMA(ah_[kk], Gzh[kk], zz, 0, 0, 0);
                gi = MFMA(ac_[kk], Gni[kk], gi, 0, 0, 0);
                gh = MFMA(ah_[kk], Gnh[kk], gh, 0, 0, 0);
            }
#pragma unroll
            for (int j = 0; j < 4; ++j){
                uint32_t r = (uint32_t)(m * 16 + u * 4 + j);
                uint32_t inner = swz(r * 256 + (uint32_t)c * 2);
                float hold = (float)*(const bf16*)(smem + HL0 + inner);
                float rg = sigm(rr[j] + br);
                float zg = sigm(zz[j] + bz);
                float ng = tanh_fast(gi[j] + bin + rg * (gh[j] + bhn));
                *(bf16*)(smem + ALO + inner) = (bf16)((1.f - zg) * ng + zg * hold);
            }
        }
        asm volatile("s_waitcnt lgkmcnt(0)" ::: "memory");
        __builtin_amdgcn_sched_barrier(0);
        __builtin_amdgcn_s_barrier();

        // ---- coalesced copy-out: ALO -> hNew (full-line dwordx4 stores) ----
        {
            char* hNb = (char*)hNew + (size_t)t * 32768;
#pragma unroll
            for (int i = 0; i < 4; ++i){
                uint32_t off = (uint32_t)tid * 16 + (uint32_t)i * 8192;
                *(u32x4*)(hNb + off) = *(const u32x4*)(smem + ALO + off);
            }
        }
        cur ^= 1;
    }
}

// ---------------- final MLP: 128 -> 128 (ReLU) -> 64, f32 out ----------------
__global__ __launch_bounds__(256) void k_final(
    const bf16* __restrict__ hin, const bf16* __restrict__ W1, const float* __restrict__ b1,
    const bf16* __restrict__ W2, const float* __restrict__ b2,
    float* __restrict__ out, int nTiles)
{
    __shared__ bf16 lds[NTPB][16][LDP];
    int wid = threadIdx.x >> 6, lane = threadIdx.x & 63;
    int tile = blockIdx.x * NTPB + wid;
    if (tile >= nTiles) return;
    int r0 = tile * 16;
    int rA = lane & 15, u = lane >> 4, ko = u * 8;

    // hin rows are slot-swizzled
    bf16x8 a[4];
    const char* hb = (const char*)hin;
    uint32_t b0 = (uint32_t)(r0 + rA) * 256 + (uint32_t)(u * 16);
#pragma unroll
    for (int kk = 0; kk < 4; ++kk) a[kk] = *(const bf16x8*)(hb + swz(b0 + (uint32_t)kk * 64));

#pragma unroll
    for (int t = 0; t < 8; ++t){
        f32x4 acc = {0.f, 0.f, 0.f, 0.f};
        int c = t * 16 + rA;
        const bf16* bp = W1 + (size_t)c * HD + ko;
#pragma unroll
        for (int kk = 0; kk < 4; ++kk)
            acc = MFMA(a[kk], ldb8(bp + kk * 32), acc, 0, 0, 0);
        float bias = b1[c];
#pragma unroll
        for (int j = 0; j < 4; ++j){
            float v = fmaxf(acc[j] + bias, 0.f);
            lds[wid][u * 4 + j][c] = (bf16)v;
        }
    }
    __threadfence_block();
    bf16x8 a2[4];
    const bf16* lp = &lds[wid][rA][ko];
#pragma unroll
    for (int kk = 0; kk < 4; ++kk) a2[kk] = ldb8(lp + kk * 32);

#pragma unroll
    for (int t = 0; t < 4; ++t){
        f32x4 acc = {0.f, 0.f, 0.f, 0.f};
        int c = t * 16 + rA;
        const bf16* bp = W2 + (size_t)c * HD + ko;
#pragma unroll
        for (int kk = 0; kk < 4; ++kk)
            acc = MFMA(a2[kk], ldb8(bp + kk * 32), acc, 0, 0, 0);
        float bias = b2[c];
#pragma unroll
        for (int j = 0; j < 4; ++j)
            out[(size_t)(r0 + u * 4 + j) * 64 + c] = acc[j] + bias;
    }
}

extern "C" void kernel_launch(void* const* d_in, const int* in_sizes, int n_in,
                              void* d_out, int out_size, void* d_ws, size_t ws_size,
                              hipStream_t stream)
{
    const float* x    = (const float*)d_in[0];
    const int*   src  = (const int*)d_in[1];
    const int*   dst  = (const int*)d_in[2];
    const float* lW1  = (const float*)d_in[3];
    const float* lb1  = (const float*)d_in[4];
    const float* lW2  = (const float*)d_in[5];
    const float* lb2  = (const float*)d_in[6];
    const float* gmm  = (const float*)d_in[7];
    const float* bta  = (const float*)d_in[8];
    const float* mun  = (const float*)d_in[9];
    const float* vrr  = (const float*)d_in[10];
    const float* Wih  = (const float*)d_in[11];
    const float* Whh  = (const float*)d_in[12];
    const float* bih  = (const float*)d_in[13];
    const float* bhh  = (const float*)d_in[14];
    const float* fW1  = (const float*)d_in[15];
    const float* fb1  = (const float*)d_in[16];
    const float* fW2  = (const float*)d_in[17];
    const float* fb2  = (const float*)d_in[18];

    int n  = in_sizes[0] / HD;
    int ne = in_sizes[1];
    int E  = ne / 2;                    // dst[E:2E) is sorted
    int L  = in_sizes[3] / (HD * HD);
    int nPad = (n + 127) & ~127;

    char* w = (char*)d_ws;
    auto alloc = [&](size_t bytes) -> char* {
        char* p = w; w += (bytes + 255) & ~(size_t)255; return p;
    };
    bf16* xbf  = (bf16*)alloc((size_t)nPad * HD * 2);
    bf16* hA   = (bf16*)alloc((size_t)nPad * HD * 2);
    bf16* hB   = (bf16*)alloc((size_t)nPad * HD * 2);
    bf16* cin  = (bf16*)alloc((size_t)nPad * HD * 2);
    bf16* W1b  = (bf16*)alloc((size_t)L * HD * HD * 2);
    bf16* W2b  = (bf16*)alloc((size_t)L * HD * HD * 2);
    bf16* Wib  = (bf16*)alloc((size_t)3 * HD * HD * 2);
    bf16* Whb  = (bf16*)alloc((size_t)3 * HD * HD * 2);
    bf16* fW1b = (bf16*)alloc((size_t)HD * HD * 2);
    bf16* fW2b = (bf16*)alloc((size_t)64 * HD * 2);
    int*  degB = (int*)alloc((size_t)n * 4);
    int*  rowsB= (int*)alloc((size_t)(n + 1) * 4);
    int*  rows2= (int*)alloc((size_t)(n + 1) * 4);
    int*  bsum = (int*)alloc(512);
    int*  curB = (int*)alloc((size_t)n * 4);
    int*  colB = (int*)alloc((size_t)E * 4);

    auto cvt = [&](const float* i, bf16* o, int cnt){
        k_cvt<<<(cnt + 255) / 256, 256, 0, stream>>>(i, o, cnt);
    };
    int nU = n * 64;   // u32 count of x
    k_cvt_x<<<(nU + 255) / 256, 256, 0, stream>>>(x, (uint32_t*)xbf, nU);
    cvt(lW1, W1b,  L * HD * HD);
    cvt(lW2, W2b,  L * HD * HD);
    cvt(Wih, Wib,  3 * HD * HD);
    cvt(Whh, Whb,  3 * HD * HD);
    cvt(fW1, fW1b, HD * HD);
    cvt(fW2, fW2b, 64 * HD);

    hipMemsetAsync(degB, 0, (size_t)n * 4, stream);
    hipMemsetAsync(hA, 0, (size_t)nPad * HD * 2, stream);

    k_bound<<<(n + 1 + 255) / 256, 256, 0, stream>>>(dst + E, E, rows2, n);
    k_count<<<(E + 255) / 256, 256, 0, stream>>>(dst, degB, E);
    int nb = (n + 1023) / 1024;
    k_scan1<<<nb, 256, 0, stream>>>(degB, rowsB, bsum, n);
    k_scan2<<<1, 128, 0, stream>>>(bsum, nb);
    k_scan3<<<(n + 1 + 255) / 256, 256, 0, stream>>>(rowsB, bsum, n, E);
    hipMemcpyAsync(curB, rowsB, (size_t)n * 4, hipMemcpyDeviceToDevice, stream);
    int nPerG = (n + 7) / 8;
    k_fillp<<<8 * ((E + 255) / 256), 256, 0, stream>>>(src, dst, curB, colB, E, nPerG);

    int nT128 = nPad / 128;
    int nT16 = (n + 15) / 16;
    int gF = (nT16 + NTPB - 1) / NTPB;

    const bf16* curp = xbf;
    for (int l = 0; l < L; ++l){
        k_gather<<<(n + 3) / 4, 256, 0, stream>>>(curp, src + E, rows2, colB, rowsB, cin, n);
        k_layer<<<256, 512, 0, stream>>>(cin, hA, hB,
            W1b + (size_t)l * HD * HD, lb1 + l * HD,
            W2b + (size_t)l * HD * HD, lb2 + l * HD,
            gmm + l * HD, bta + l * HD, mun + l * HD, vrr + l * HD,
            Wib, Whb, bih, bhh, nT128);
        bf16* tmp = hA; hA = hB; hB = tmp;
        curp = hA;
    }
    k_final<<<gF, 256, 0, stream>>>(hA, fW1b, fb1, fW2b, fb2, (float*)d_out, nT16);
}